// Round 4
// baseline (7131.553 us; speedup 1.0000x reference)
//
#include <hip/hip_runtime.h>

// Round 4: ZERO-workspace build. One kernel, launched 4x (h=0..3), grid=1024 (b).
// Per block: QKV MFMA -> VALU S1 (inline bias) -> P1V -> S2 -> stage proj_w^T
// slice -> P2A + dwconv + fused per-head proj, RMW into d_out (fp32).
// h=0 initializes out = proj_b + partial; h>=1 accumulates. No d_ws use at all.

typedef __attribute__((ext_vector_type(8))) short bf16x8;
typedef __attribute__((ext_vector_type(4))) float f32x4;

#define OFF_Q 0          // Q [169][64] bf16, stride 128B
#define OFF_K 22528      // K [169][64]
#define OFF_V 45056      // V [169][64]
#define OFF_A 67584      // agent_v [169][64]
#define OFF_P 90112      // P [169][176] bf16, stride 352B; QKV-w staging overlay (192x80B)
#define OFF_W 0          // Wt [64][256] bf16 = 32KB, overlays Q+K after S2
#define SMEM_BYTES 149600

__device__ __forceinline__ unsigned short f2bf(float f) {
  unsigned int u = __float_as_uint(f);
  u += 0x7FFFu + ((u >> 16) & 1u);
  return (unsigned short)(u >> 16);
}
__device__ __forceinline__ float bf2f(unsigned short v) {
  return __uint_as_float(((unsigned int)v) << 16);
}
__device__ __forceinline__ f32x4 mfma16(bf16x8 a, bf16x8 b, f32x4 c) {
  return __builtin_amdgcn_mfma_f32_16x16x32_bf16(a, b, c, 0, 0, 0);
}
__device__ __forceinline__ bf16x8 cvt8(float4 a, float4 b) {
  bf16x8 v;
  v[0] = (short)f2bf(a.x); v[1] = (short)f2bf(a.y);
  v[2] = (short)f2bf(a.z); v[3] = (short)f2bf(a.w);
  v[4] = (short)f2bf(b.x); v[5] = (short)f2bf(b.y);
  v[6] = (short)f2bf(b.z); v[7] = (short)f2bf(b.w);
  return v;
}

__global__ __launch_bounds__(384, 1) void attn_kernel(
    const float* __restrict__ x, const float* __restrict__ qkv_w,
    const float* __restrict__ proj_w, const float* __restrict__ proj_b,
    const float* __restrict__ dwc_w, const float* __restrict__ dwc_b,
    const float* __restrict__ an, const float* __restrict__ ah,
    const float* __restrict__ aw, const float* __restrict__ na,
    const float* __restrict__ ha, const float* __restrict__ wa,
    float* __restrict__ out, int h, int init)
{
  __shared__ __align__(16) char sm[SMEM_BYTES];
  const int b = blockIdx.x;
  const int tid = threadIdx.x;
  const int wave = tid >> 6;
  const int lane = tid & 63;
  const int l15 = lane & 15;
  const int l4 = lane >> 4;

  const int mt0 = wave * 2;
  const int mt1 = wave * 2 + 1;   // ==11 for wave 5 -> skipped
  const float* xb = x + (size_t)b * 169 * 256;

  // ---- Phase 1: QKV MFMA gemm: [176 x 192(3*64)] = x[b] @ w_head^T ----
  {
    f32x4 acc0[12], acc1[12];
    const f32x4 z = {0.f, 0.f, 0.f, 0.f};
#pragma unroll
    for (int i = 0; i < 12; ++i) { acc0[i] = z; acc1[i] = z; }

    const int arow0 = mt0 * 16 + l15;
    const int arow1 = mt1 * 16 + l15;
    const int gr0 = arow0 < 169 ? arow0 : 168;
    const int gr1 = arow1 < 169 ? arow1 : 168;

    for (int ks = 0; ks < 8; ++ks) {
      // stage qkv_w slice [192 rows][32 k] fp32->bf16 into OFF_P overlay (stride 80B)
      {
        const int row = tid >> 1;          // 0..191
        const int half = tid & 1;
        const int grow = ((row >> 6) << 8) + h * 64 + (row & 63);  // q/k/v sections
        const float* src = qkv_w + grow * 256 + ks * 32 + half * 16;
        float4 f0 = *(const float4*)(src);
        float4 f1 = *(const float4*)(src + 4);
        float4 f2 = *(const float4*)(src + 8);
        float4 f3 = *(const float4*)(src + 12);
        char* dst = sm + OFF_P + row * 80 + half * 32;
        *(bf16x8*)(dst) = cvt8(f0, f1);
        *(bf16x8*)(dst + 16) = cvt8(f2, f3);
      }
      __syncthreads();
      bf16x8 af0, af1;
      {
        const float* p0 = xb + gr0 * 256 + ks * 32 + l4 * 8;
        af0 = cvt8(*(const float4*)p0, *(const float4*)(p0 + 4));
      }
      {
        const float* p1 = xb + gr1 * 256 + ks * 32 + l4 * 8;
        af1 = cvt8(*(const float4*)p1, *(const float4*)(p1 + 4));
      }
#pragma unroll
      for (int nt = 0; nt < 12; ++nt) {
        bf16x8 bw = *(const bf16x8*)(sm + OFF_P + (nt * 16 + l15) * 80 + l4 * 16);
        acc0[nt] = mfma16(af0, bw, acc0[nt]);
        if (mt1 < 11) acc1[nt] = mfma16(af1, bw, acc1[nt]);
      }
      __syncthreads();
    }
    // write Q, K, V plain row-major [n][d], stride 128B, skip pad rows
#pragma unroll
    for (int nt = 0; nt < 12; ++nt) {
      const int mat = nt >> 2;
      const int base = (mat == 0) ? OFF_Q : (mat == 1) ? OFF_K : OFF_V;
      const int d = (nt & 3) * 16 + l15;
#pragma unroll
      for (int r = 0; r < 4; ++r) {
        const int n0 = mt0 * 16 + l4 * 4 + r;
        if (n0 < 169)
          *(unsigned short*)(sm + base + n0 * 128 + d * 2) = f2bf(acc0[nt][r]);
        if (mt1 < 11) {
          const int n1 = mt1 * 16 + l4 * 4 + r;
          if (n1 < 169)
            *(unsigned short*)(sm + base + n1 * 128 + d * 2) = f2bf(acc1[nt][r]);
        }
      }
    }
  }
  __syncthreads();

  // ---- Phase 2: S1 (rows=agents a, cols=tokens n), inline bias, softmax -> P ----
  for (int row = wave; row < 169; row += 6) {
    float sv[3];
#pragma unroll
    for (int cc = 0; cc < 3; ++cc) {
      const int col = cc * 64 + lane;
      if (col < 169) {
        float acc = 0.f;
        const int l8 = lane & 7;
#pragma unroll
        for (int t = 0; t < 8; ++t) {
          const int ch = ((l8 + t) & 7) * 16;
          bf16x8 qv = *(const bf16x8*)(sm + OFF_Q + row * 128 + ch);
          bf16x8 bv = *(const bf16x8*)(sm + OFF_K + col * 128 + ch);
#pragma unroll
          for (int j = 0; j < 8; ++j)
            acc += bf2f((unsigned short)qv[j]) * bf2f((unsigned short)bv[j]);
        }
        const int yc = (col * 79) >> 10;        // col/13
        const int xc = col - yc * 13;
        const float bias = an[h * 28561 + row * 169 + col]
                         + ah[(h * 169 + row) * 13 + yc]
                         + aw[(h * 169 + row) * 13 + xc];
        sv[cc] = acc * 0.125f + bias;
      } else {
        sv[cc] = -1e30f;
      }
    }
    float m = fmaxf(sv[0], fmaxf(sv[1], sv[2]));
#pragma unroll
    for (int off = 1; off < 64; off <<= 1) m = fmaxf(m, __shfl_xor(m, off));
    float sum = 0.f;
#pragma unroll
    for (int cc = 0; cc < 3; ++cc) {
      const int col = cc * 64 + lane;
      const float e = (col < 169) ? __expf(sv[cc] - m) : 0.f;
      sv[cc] = e; sum += e;
    }
#pragma unroll
    for (int off = 1; off < 64; off <<= 1) sum += __shfl_xor(sum, off);
    const float inv = 1.f / sum;
#pragma unroll
    for (int cc = 0; cc < 3; ++cc) {
      const int col = cc * 64 + lane;
      if (col < 169)
        *(unsigned short*)(sm + OFF_P + row * 352 + col * 2) = f2bf(sv[cc] * inv);
    }
  }
  __syncthreads();

  // ---- Phase 3: P1V: agent_v[a][d] = sum_n P[a][n] * V[n][d]; lane = d ----
  for (int row = wave; row < 169; row += 6) {
    float acc = 0.f;
    for (int nb = 0; nb < 21; ++nb) {
      bf16x8 p8 = *(const bf16x8*)(sm + OFF_P + row * 352 + nb * 16);
#pragma unroll
      for (int j = 0; j < 8; ++j)
        acc += bf2f((unsigned short)p8[j]) *
               bf2f(*(const unsigned short*)(sm + OFF_V + (nb * 8 + j) * 128 + lane * 2));
    }
    acc += bf2f(*(const unsigned short*)(sm + OFF_P + row * 352 + 168 * 2)) *
           bf2f(*(const unsigned short*)(sm + OFF_V + 168 * 128 + lane * 2));
    *(unsigned short*)(sm + OFF_A + row * 128 + lane * 2) = f2bf(acc);
  }
  __syncthreads();

  // ---- Phase 4: S2 (rows=tokens n, cols=agents a), B-operand = Q, inline bias ----
  for (int row = wave; row < 169; row += 6) {
    const int yn = (row * 79) >> 10;
    const int xn = row - yn * 13;
    float sv[3];
#pragma unroll
    for (int cc = 0; cc < 3; ++cc) {
      const int col = cc * 64 + lane;
      if (col < 169) {
        float acc = 0.f;
        const int l8 = lane & 7;
#pragma unroll
        for (int t = 0; t < 8; ++t) {
          const int ch = ((l8 + t) & 7) * 16;
          bf16x8 qv = *(const bf16x8*)(sm + OFF_Q + row * 128 + ch);
          bf16x8 bv = *(const bf16x8*)(sm + OFF_Q + col * 128 + ch);
#pragma unroll
          for (int j = 0; j < 8; ++j)
            acc += bf2f((unsigned short)qv[j]) * bf2f((unsigned short)bv[j]);
        }
        const float bias = na[h * 28561 + col * 169 + row]
                         + ha[(h * 13 + yn) * 169 + col]
                         + wa[(h * 13 + xn) * 169 + col];
        sv[cc] = acc * 0.125f + bias;
      } else {
        sv[cc] = -1e30f;
      }
    }
    float m = fmaxf(sv[0], fmaxf(sv[1], sv[2]));
#pragma unroll
    for (int off = 1; off < 64; off <<= 1) m = fmaxf(m, __shfl_xor(m, off));
    float sum = 0.f;
#pragma unroll
    for (int cc = 0; cc < 3; ++cc) {
      const int col = cc * 64 + lane;
      const float e = (col < 169) ? __expf(sv[cc] - m) : 0.f;
      sv[cc] = e; sum += e;
    }
#pragma unroll
    for (int off = 1; off < 64; off <<= 1) sum += __shfl_xor(sum, off);
    const float inv = 1.f / sum;
#pragma unroll
    for (int cc = 0; cc < 3; ++cc) {
      const int col = cc * 64 + lane;
      if (col < 169)
        *(unsigned short*)(sm + OFF_P + row * 352 + col * 2) = f2bf(sv[cc] * inv);
    }
  }
  __syncthreads();

  // ---- Phase 5: stage Wt[d][256] (d = this head's 64 proj_w columns), bf16 ----
  // Wt[d][j] = proj_w[j][h*64+d]; row stride 512B. Overlays dead Q+K regions.
  for (int idx = tid; idx < 2048; idx += 384) {
    const int j = idx >> 3;          // 0..255
    const int c8 = idx & 7;          // 0..7 -> d block of 8
    const float* src = proj_w + j * 256 + h * 64 + c8 * 8;
#pragma unroll
    for (int e = 0; e < 8; ++e)
      *(unsigned short*)(sm + OFF_W + (c8 * 8 + e) * 512 + j * 2) = f2bf(src[e]);
  }
  __syncthreads();

  // ---- Phase 6: P2A + dwconv + fused proj, RMW d_out; lane = d ----
  for (int row = wave; row < 169; row += 6) {
    float acc = 0.f;
    for (int nb = 0; nb < 21; ++nb) {
      bf16x8 p8 = *(const bf16x8*)(sm + OFF_P + row * 352 + nb * 16);
#pragma unroll
      for (int j = 0; j < 8; ++j)
        acc += bf2f((unsigned short)p8[j]) *
               bf2f(*(const unsigned short*)(sm + OFF_A + (nb * 8 + j) * 128 + lane * 2));
    }
    acc += bf2f(*(const unsigned short*)(sm + OFF_P + row * 352 + 168 * 2)) *
           bf2f(*(const unsigned short*)(sm + OFF_A + 168 * 128 + lane * 2));

    const int c = h * 64 + lane;
    const int y = (row * 79) >> 10;
    const int xx = row - y * 13;
    float dw = dwc_b[c];
#pragma unroll
    for (int ky = 0; ky < 3; ++ky) {
      const int yy = y + ky - 1;
      if ((unsigned)yy >= 13u) continue;
#pragma unroll
      for (int kx = 0; kx < 3; ++kx) {
        const int x2 = xx + kx - 1;
        if ((unsigned)x2 >= 13u) continue;
        dw += dwc_w[c * 9 + ky * 3 + kx] *
              bf2f(*(const unsigned short*)(sm + OFF_V + (yy * 13 + x2) * 128 + lane * 2));
      }
    }
    const float act = acc + dw;       // pre-proj activation, this head's d=lane slice

    // proj partial: out[row][j] += sum_d act[d] * Wt[d][j]
    float pacc0 = 0.f, pacc1 = 0.f, pacc2 = 0.f, pacc3 = 0.f;
    for (int d = 0; d < 64; ++d) {
      const float av = __shfl(act, d);
      const char* wrow = sm + OFF_W + d * 512;
      pacc0 += av * bf2f(*(const unsigned short*)(wrow + (lane) * 2));
      pacc1 += av * bf2f(*(const unsigned short*)(wrow + (64 + lane) * 2));
      pacc2 += av * bf2f(*(const unsigned short*)(wrow + (128 + lane) * 2));
      pacc3 += av * bf2f(*(const unsigned short*)(wrow + (192 + lane) * 2));
    }
    const size_t gbase = ((size_t)b * 169 + row) * 256;
    if (init) {
      out[gbase + lane]       = pacc0 + proj_b[lane];
      out[gbase + 64 + lane]  = pacc1 + proj_b[64 + lane];
      out[gbase + 128 + lane] = pacc2 + proj_b[128 + lane];
      out[gbase + 192 + lane] = pacc3 + proj_b[192 + lane];
    } else {
      out[gbase + lane]       += pacc0;
      out[gbase + 64 + lane]  += pacc1;
      out[gbase + 128 + lane] += pacc2;
      out[gbase + 192 + lane] += pacc3;
    }
  }
}

extern "C" void kernel_launch(void* const* d_in, const int* in_sizes, int n_in,
                              void* d_out, int out_size, void* d_ws, size_t ws_size,
                              hipStream_t stream) {
  const float* x      = (const float*)d_in[0];
  const float* qkv_w  = (const float*)d_in[1];
  const float* proj_w = (const float*)d_in[2];
  const float* proj_b = (const float*)d_in[3];
  const float* dwc_w  = (const float*)d_in[4];
  const float* dwc_b  = (const float*)d_in[5];
  const float* an     = (const float*)d_in[6];
  const float* na     = (const float*)d_in[7];
  const float* ah     = (const float*)d_in[8];
  const float* aw     = (const float*)d_in[9];
  const float* ha     = (const float*)d_in[10];
  const float* wa     = (const float*)d_in[11];
  float* outp = (float*)d_out;

  for (int h = 0; h < 4; ++h) {
    attn_kernel<<<1024, 384, 0, stream>>>(
        x, qkv_w, proj_w, proj_b, dwc_w, dwc_b,
        an, ah, aw, na, ha, wa, outp, h, h == 0 ? 1 : 0);
  }
}

// Round 5
// 4629.127 us; speedup vs baseline: 1.5406x; 1.5406x over previous
//
#include <hip/hip_runtime.h>

// Round 5: single launch, zero workspace, all-MFMA fused agent attention.
// grid = 1024 (one block per batch b), 384 threads, ~158KB LDS.
// Per block, for h=0..3: QKV MFMA -> S1 (MFMA + inline bias + wave softmax)
// -> P1V MFMA -> S2 MFMA -> P2A MFMA + dwconv -> per-head proj-partial MFMA
// accumulated in registers. Final: out = accP + proj_b (fp32), written once.

typedef __attribute__((ext_vector_type(8))) short bf16x8;
typedef __attribute__((ext_vector_type(4))) float f32x4;

#define OFF_Q 0          // Q [176][64] bf16 stride 128B (swizzled); later act[n][64]
#define OFF_K 22528      // K [176][64] stride 128B
#define OFF_V 45056      // Vt [64][192] stride 384B (transposed V)
#define OFF_A 69632      // agent_v^T [64][192] stride 384B
#define OFF_P 94208      // P [176][192] stride 384B; qkv_w staging (192x80B) and W staging (256x128B) overlay
#define SMEM_BYTES 161792

__device__ __forceinline__ unsigned short f2bf(float f) {
  unsigned int u = __float_as_uint(f);
  u += 0x7FFFu + ((u >> 16) & 1u);
  return (unsigned short)(u >> 16);
}
__device__ __forceinline__ float bf2f(unsigned short v) {
  return __uint_as_float(((unsigned int)v) << 16);
}
__device__ __forceinline__ f32x4 mfma16(bf16x8 a, bf16x8 b, f32x4 c) {
  return __builtin_amdgcn_mfma_f32_16x16x32_bf16(a, b, c, 0, 0, 0);
}
__device__ __forceinline__ bf16x8 cvt8(float4 a, float4 b) {
  bf16x8 v;
  v[0] = (short)f2bf(a.x); v[1] = (short)f2bf(a.y);
  v[2] = (short)f2bf(a.z); v[3] = (short)f2bf(a.w);
  v[4] = (short)f2bf(b.x); v[5] = (short)f2bf(b.y);
  v[6] = (short)f2bf(b.z); v[7] = (short)f2bf(b.w);
  return v;
}
// swizzled LDS helpers: addr = base + row*stride + (colbyte ^ ((row&7)<<4))
__device__ __forceinline__ bf16x8 ld8s(const char* sm, int base, int stride, int row, int colbyte) {
  return *(const bf16x8*)(sm + base + row * stride + (colbyte ^ ((row & 7) << 4)));
}
__device__ __forceinline__ void st2s(char* sm, int base, int stride, int row, int col, unsigned short v) {
  *(unsigned short*)(sm + base + row * stride + ((col * 2) ^ ((row & 7) << 4))) = v;
}
__device__ __forceinline__ float ld2s(const char* sm, int base, int stride, int row, int col) {
  return bf2f(*(const unsigned short*)(sm + base + row * stride + ((col * 2) ^ ((row & 7) << 4))));
}

__global__ __launch_bounds__(384, 1) void attn_kernel(
    const float* __restrict__ x, const float* __restrict__ qkv_w,
    const float* __restrict__ proj_w, const float* __restrict__ proj_b,
    const float* __restrict__ dwc_w, const float* __restrict__ dwc_b,
    const float* __restrict__ an, const float* __restrict__ ah,
    const float* __restrict__ aw, const float* __restrict__ na,
    const float* __restrict__ ha, const float* __restrict__ wa,
    float* __restrict__ out)
{
  __shared__ __align__(16) char sm[SMEM_BYTES];
  const int b = blockIdx.x;
  const int tid = threadIdx.x;
  const int wave = tid >> 6;
  const int lane = tid & 63;
  const int l15 = lane & 15;
  const int l4 = lane >> 4;
  const int mt0 = wave * 2;
  const int mt1 = wave * 2 + 1;   // ==11 for wave 5 -> skipped
  const float* xb = x + (size_t)b * 169 * 256;

  // zero all LDS once (logical pad cols of V/A must be zero; bijective swizzle
  // keeps them zero across heads since stores never target logical pads)
  {
    int* p = (int*)sm;
    for (int i = tid; i < SMEM_BYTES / 4; i += 384) p[i] = 0;
  }

  f32x4 accP[2][16];          // proj accumulator, persists across heads
  const f32x4 z = {0.f, 0.f, 0.f, 0.f};
#pragma unroll
  for (int i = 0; i < 2; ++i)
#pragma unroll
    for (int j = 0; j < 16; ++j) accP[i][j] = z;

  for (int h = 0; h < 4; ++h) {
    __syncthreads();   // protect region reuse across heads (and after LDS zero)

    // ---- Phase 1: QKV MFMA: [176 x 192(3*64)] = x[b] @ w_head^T ----
    {
      f32x4 acc0[12], acc1[12];
#pragma unroll
      for (int i = 0; i < 12; ++i) { acc0[i] = z; acc1[i] = z; }

      const int arow0 = mt0 * 16 + l15;
      const int arow1 = mt1 * 16 + l15;
      const int gr0 = arow0 < 169 ? arow0 : 168;
      const int gr1 = arow1 < 169 ? arow1 : 168;

      for (int ks = 0; ks < 8; ++ks) {
        {   // stage qkv_w slice [192 rows][32 k] fp32->bf16, linear stride 80B
          const int row = tid >> 1;
          const int half = tid & 1;
          const int grow = ((row >> 6) << 8) + h * 64 + (row & 63);
          const float* src = qkv_w + grow * 256 + ks * 32 + half * 16;
          float4 f0 = *(const float4*)(src);
          float4 f1 = *(const float4*)(src + 4);
          float4 f2 = *(const float4*)(src + 8);
          float4 f3 = *(const float4*)(src + 12);
          char* dst = sm + OFF_P + row * 80 + half * 32;
          *(bf16x8*)(dst) = cvt8(f0, f1);
          *(bf16x8*)(dst + 16) = cvt8(f2, f3);
        }
        __syncthreads();
        bf16x8 af0, af1;
        {
          const float* p0 = xb + gr0 * 256 + ks * 32 + l4 * 8;
          af0 = cvt8(*(const float4*)p0, *(const float4*)(p0 + 4));
        }
        {
          const float* p1 = xb + gr1 * 256 + ks * 32 + l4 * 8;
          af1 = cvt8(*(const float4*)p1, *(const float4*)(p1 + 4));
        }
#pragma unroll
        for (int nt = 0; nt < 12; ++nt) {
          bf16x8 bw = *(const bf16x8*)(sm + OFF_P + (nt * 16 + l15) * 80 + l4 * 16);
          acc0[nt] = mfma16(af0, bw, acc0[nt]);
          if (mt1 < 11) acc1[nt] = mfma16(af1, bw, acc1[nt]);
        }
        __syncthreads();
      }
      // write Q,K row-major [n][d] (stride 128, swizzled); V transposed [d][n] (stride 384)
#pragma unroll
      for (int nt = 0; nt < 12; ++nt) {
        const int mat = nt >> 2;
        const int d = (nt & 3) * 16 + l15;
#pragma unroll
        for (int r = 0; r < 4; ++r) {
          {
            const int n = mt0 * 16 + l4 * 4 + r;
            const unsigned short u = f2bf(acc0[nt][r]);
            if (mat == 0)      st2s(sm, OFF_Q, 128, n, d, u);
            else if (mat == 1) st2s(sm, OFF_K, 128, n, d, u);
            else               st2s(sm, OFF_V, 384, d, n, u);
          }
          if (mt1 < 11) {
            const int n = mt1 * 16 + l4 * 4 + r;
            const unsigned short u = f2bf(acc1[nt][r]);
            if (mat == 0)      st2s(sm, OFF_Q, 128, n, d, u);
            else if (mat == 1) st2s(sm, OFF_K, 128, n, d, u);
            else               st2s(sm, OFF_V, 384, d, n, u);
          }
        }
      }
    }
    __syncthreads();

    // ---- S-phase (shared): S = 0.125*Q@B^T + bias, row softmax -> P ----
    // which==0: S1 rows=agents, cols=tokens, B=K. which==1: S2 rows=tokens, cols=agents, B=Q.
    auto sphase = [&](int srcBase, int which) {
#pragma unroll
      for (int mi = 0; mi < 2; ++mi) {
        const int mt = wave * 2 + mi;
        if (mt >= 11) continue;
        const int arow = mt * 16 + l15;
        bf16x8 a0 = ld8s(sm, OFF_Q, 128, arow, l4 * 16);
        bf16x8 a1 = ld8s(sm, OFF_Q, 128, arow, 64 + l4 * 16);
        f32x4 s[11];
#pragma unroll
        for (int nt = 0; nt < 11; ++nt) {
          const int brow = nt * 16 + l15;
          bf16x8 b0 = ld8s(sm, srcBase, 128, brow, l4 * 16);
          bf16x8 b1 = ld8s(sm, srcBase, 128, brow, 64 + l4 * 16);
          f32x4 c = z;
          c = mfma16(a0, b0, c);
          c = mfma16(a1, b1, c);
          s[nt] = c;
        }
        const int rbase = mt * 16 + l4 * 4;
#pragma unroll
        for (int nt = 0; nt < 11; ++nt) {
          const int cc = nt * 16 + l15;
          const int ccl = cc > 168 ? 168 : cc;
          const int yc = (ccl * 79) >> 10;   // ccl/13
          const int xc = ccl - yc * 13;
#pragma unroll
          for (int r = 0; r < 4; ++r) {
            const int rr = rbase + r;
            const int rrl = rr > 168 ? 168 : rr;
            float bias;
            if (which == 0) {
              bias = an[h * 28561 + rrl * 169 + ccl]
                   + ah[(h * 169 + rrl) * 13 + yc]
                   + aw[(h * 169 + rrl) * 13 + xc];
            } else {
              const int yn = (rrl * 79) >> 10;
              const int xn = rrl - yn * 13;
              bias = na[h * 28561 + ccl * 169 + rrl]
                   + ha[(h * 13 + yn) * 169 + ccl]
                   + wa[(h * 13 + xn) * 169 + ccl];
            }
            const float v = s[nt][r] * 0.125f + bias;
            s[nt][r] = (cc > 168) ? -1e30f : v;
          }
        }
#pragma unroll
        for (int r = 0; r < 4; ++r) {
          float m = s[0][r];
#pragma unroll
          for (int nt = 1; nt < 11; ++nt) m = fmaxf(m, s[nt][r]);
          m = fmaxf(m, __shfl_xor(m, 1));
          m = fmaxf(m, __shfl_xor(m, 2));
          m = fmaxf(m, __shfl_xor(m, 4));
          m = fmaxf(m, __shfl_xor(m, 8));
          float sum = 0.f;
#pragma unroll
          for (int nt = 0; nt < 11; ++nt) { const float e = __expf(s[nt][r] - m); s[nt][r] = e; sum += e; }
          sum += __shfl_xor(sum, 1);
          sum += __shfl_xor(sum, 2);
          sum += __shfl_xor(sum, 4);
          sum += __shfl_xor(sum, 8);
          const float inv = 1.f / sum;
#pragma unroll
          for (int nt = 0; nt < 11; ++nt) s[nt][r] *= inv;
        }
#pragma unroll
        for (int nt = 0; nt < 11; ++nt)
#pragma unroll
          for (int r = 0; r < 4; ++r)
            st2s(sm, OFF_P, 384, rbase + r, nt * 16 + l15, f2bf(s[nt][r]));
#pragma unroll
        for (int r = 0; r < 4; ++r)     // zero logical pad cols 176..191
          st2s(sm, OFF_P, 384, rbase + r, 176 + l15, 0);
      }
    };

    sphase(OFF_K, 0);        // S1: agent attention
    __syncthreads();

    // ---- P1V: agent_v = P1 @ V -> store transposed into OFF_A ----
#pragma unroll
    for (int mi = 0; mi < 2; ++mi) {
      const int mt = wave * 2 + mi;
      if (mt >= 11) continue;
      const int arow = mt * 16 + l15;
      f32x4 o[4];
#pragma unroll
      for (int i = 0; i < 4; ++i) o[i] = z;
#pragma unroll
      for (int ks = 0; ks < 6; ++ks) {
        bf16x8 a = ld8s(sm, OFF_P, 384, arow, ks * 64 + l4 * 16);
#pragma unroll
        for (int nt = 0; nt < 4; ++nt) {
          bf16x8 bv = ld8s(sm, OFF_V, 384, nt * 16 + l15, ks * 64 + l4 * 16);
          o[nt] = mfma16(a, bv, o[nt]);
        }
      }
#pragma unroll
      for (int nt = 0; nt < 4; ++nt)
#pragma unroll
        for (int r = 0; r < 4; ++r)
          st2s(sm, OFF_A, 384, nt * 16 + l15, mt * 16 + l4 * 4 + r, f2bf(o[nt][r]));
    }
    __syncthreads();

    sphase(OFF_Q, 1);        // S2: q attention (B operand = Q itself)
    __syncthreads();

    // ---- P2A + dwconv -> act[n][64] into OFF_Q region (Q dead after S2) ----
#pragma unroll
    for (int mi = 0; mi < 2; ++mi) {
      const int mt = wave * 2 + mi;
      if (mt >= 11) continue;
      const int arow = mt * 16 + l15;
      f32x4 o[4];
#pragma unroll
      for (int i = 0; i < 4; ++i) o[i] = z;
#pragma unroll
      for (int ks = 0; ks < 6; ++ks) {
        bf16x8 a = ld8s(sm, OFF_P, 384, arow, ks * 64 + l4 * 16);
#pragma unroll
        for (int nt = 0; nt < 4; ++nt) {
          bf16x8 bv = ld8s(sm, OFF_A, 384, nt * 16 + l15, ks * 64 + l4 * 16);
          o[nt] = mfma16(a, bv, o[nt]);
        }
      }
#pragma unroll
      for (int nt = 0; nt < 4; ++nt) {
        const int d = nt * 16 + l15;
        const int c = h * 64 + d;
        const float bc = dwc_b[c];
#pragma unroll
        for (int r = 0; r < 4; ++r) {
          const int n = mt * 16 + l4 * 4 + r;
          const int nl = n > 168 ? 168 : n;
          const int y = (nl * 79) >> 10;
          const int xx = nl - y * 13;
          float dw = bc;
#pragma unroll
          for (int ky = 0; ky < 3; ++ky) {
            const int yy = y + ky - 1;
            if ((unsigned)yy >= 13u) continue;
#pragma unroll
            for (int kx = 0; kx < 3; ++kx) {
              const int x2 = xx + kx - 1;
              if ((unsigned)x2 >= 13u) continue;
              dw += dwc_w[c * 9 + ky * 3 + kx] * ld2s(sm, OFF_V, 384, d, yy * 13 + x2);
            }
          }
          st2s(sm, OFF_Q, 128, n, d, f2bf(o[nt][r] + dw));   // act
        }
      }
    }
    __syncthreads();

    // ---- stage Wt[j][64] = proj_w[j][h*64+d] into OFF_P (P dead), stride 128B ----
    for (int idx = tid; idx < 2048; idx += 384) {
      const int j = idx >> 3;          // 0..255
      const int c8 = idx & 7;          // 8-elem chunk of d
      const float* src = proj_w + j * 256 + h * 64 + c8 * 8;
      float4 f0 = *(const float4*)(src);
      float4 f1 = *(const float4*)(src + 4);
      *(bf16x8*)(sm + OFF_P + j * 128 + ((c8 * 16) ^ ((j & 7) << 4))) = cvt8(f0, f1);
    }
    __syncthreads();

    // ---- proj partial MFMA: accP += act @ Wt^T  (M=176, N=256, K=64) ----
#pragma unroll
    for (int mi = 0; mi < 2; ++mi) {
      const int mt = wave * 2 + mi;
      if (mt >= 11) continue;
      const int arow = mt * 16 + l15;
      bf16x8 af0 = ld8s(sm, OFF_Q, 128, arow, l4 * 16);
      bf16x8 af1 = ld8s(sm, OFF_Q, 128, arow, 64 + l4 * 16);
#pragma unroll
      for (int nt = 0; nt < 16; ++nt) {
        const int brow = nt * 16 + l15;
        bf16x8 bf0 = ld8s(sm, OFF_P, 128, brow, l4 * 16);
        bf16x8 bf1 = ld8s(sm, OFF_P, 128, brow, 64 + l4 * 16);
        accP[mi][nt] = mfma16(af0, bf0, accP[mi][nt]);
        accP[mi][nt] = mfma16(af1, bf1, accP[mi][nt]);
      }
    }
    // next head's loop-start barrier protects W/act regions
  }

  // ---- final write: out = accP + proj_b (fp32), written once ----
#pragma unroll
  for (int mi = 0; mi < 2; ++mi) {
    const int mt = wave * 2 + mi;
    if (mt >= 11) continue;
#pragma unroll
    for (int nt = 0; nt < 16; ++nt) {
      const int col = nt * 16 + l15;
      const float bias = proj_b[col];
#pragma unroll
      for (int r = 0; r < 4; ++r) {
        const int n = mt * 16 + l4 * 4 + r;
        if (n < 169)
          out[((size_t)b * 169 + n) * 256 + col] = accP[mi][nt][r] + bias;
      }
    }
  }
}

extern "C" void kernel_launch(void* const* d_in, const int* in_sizes, int n_in,
                              void* d_out, int out_size, void* d_ws, size_t ws_size,
                              hipStream_t stream) {
  const float* x      = (const float*)d_in[0];
  const float* qkv_w  = (const float*)d_in[1];
  const float* proj_w = (const float*)d_in[2];
  const float* proj_b = (const float*)d_in[3];
  const float* dwc_w  = (const float*)d_in[4];
  const float* dwc_b  = (const float*)d_in[5];
  const float* an     = (const float*)d_in[6];
  const float* na     = (const float*)d_in[7];
  const float* ah     = (const float*)d_in[8];
  const float* aw     = (const float*)d_in[9];
  const float* ha     = (const float*)d_in[10];
  const float* wa     = (const float*)d_in[11];

  attn_kernel<<<1024, 384, 0, stream>>>(
      x, qkv_w, proj_w, proj_b, dwc_w, dwc_b,
      an, ah, aw, na, ha, wa, (float*)d_out);
}